// Round 1
// baseline (2273.355 us; speedup 1.0000x reference)
//
#include <hip/hip_runtime.h>
#include <hip/hip_bf16.h>
#include <cmath>

#define NN 100000
#define EE 1250000
#define FIN 500
#define HH 64
#define CC 40
#define LL 16
#define ALPHA_C 0.1f

// ---------------- CSR build ----------------

__global__ void init_cnt_k(int* __restrict__ cnt) {
    int i = blockIdx.x * blockDim.x + threadIdx.x;
    if (i < NN) cnt[i] = 1;  // self-loop
}

__global__ void count_edges_k(const int* __restrict__ rows, int* __restrict__ cnt) {
    int e = blockIdx.x * blockDim.x + threadIdx.x;
    if (e < EE) atomicAdd(&cnt[rows[e]], 1);
}

__global__ void dinv_k(const int* __restrict__ cnt, float* __restrict__ dinv) {
    int i = blockIdx.x * blockDim.x + threadIdx.x;
    if (i < NN) dinv[i] = rsqrtf((float)cnt[i]);  // cnt >= 1 always
}

__global__ __launch_bounds__(1024) void scan_k(const int* __restrict__ cnt, int* __restrict__ row_ptr) {
    __shared__ int part[1024];
    const int T = 1024;
    int tid = threadIdx.x;
    const int chunk = (NN + T - 1) / T;  // 98
    int start = tid * chunk;
    int end = min(start + chunk, NN);
    int s = 0;
    for (int i = start; i < end; ++i) s += cnt[i];
    part[tid] = s;
    __syncthreads();
    for (int ofs = 1; ofs < T; ofs <<= 1) {
        int v = (tid >= ofs) ? part[tid - ofs] : 0;
        __syncthreads();
        part[tid] += v;
        __syncthreads();
    }
    int run = (tid > 0) ? part[tid - 1] : 0;
    for (int i = start; i < end; ++i) { row_ptr[i] = run; run += cnt[i]; }
    if (tid == T - 1) row_ptr[NN] = run;
}

__global__ void fill_self_k(const int* __restrict__ row_ptr, const float* __restrict__ dinv,
                            int2* __restrict__ edata, int* __restrict__ cur) {
    int i = blockIdx.x * blockDim.x + threadIdx.x;
    if (i < NN) {
        int p = row_ptr[i];
        float d = dinv[i];
        edata[p] = make_int2(i, __float_as_int(d * d));
        cur[i] = p + 1;
    }
}

__global__ void fill_edges_k(const int* __restrict__ rows, const int* __restrict__ cols,
                             const float* __restrict__ dinv, int* __restrict__ cur,
                             int2* __restrict__ edata) {
    int e = blockIdx.x * blockDim.x + threadIdx.x;
    if (e < EE) {
        int r = rows[e], c = cols[e];
        int p = atomicAdd(&cur[r], 1);
        edata[p] = make_int2(c, __float_as_int(dinv[r] * dinv[c]));
    }
}

// ---------------- input projection: x0 = relu(X @ W0 + b0) ----------------
// 64x64 output tile per block, K-chunks of 20 (25 chunks cover K=500 exactly)

#define KT 20
__global__ __launch_bounds__(256) void proj_k(const float* __restrict__ X, const float* __restrict__ W0,
                                              const float* __restrict__ b0, float* __restrict__ x0) {
    __shared__ float As[64][KT];
    __shared__ float Bs[KT][64];
    int tid = threadIdx.x;
    int tx = tid & 15, ty = tid >> 4;
    int m0 = blockIdx.x * 64;
    float acc[4][4] = {};
    for (int k0 = 0; k0 < FIN; k0 += KT) {
        // A: 64 rows x 20 cols = 320 float4
        for (int idx = tid; idx < 64 * 5; idx += 256) {
            int r = idx / 5, c4 = idx % 5;
            int m = m0 + r;
            float4 v = make_float4(0.f, 0.f, 0.f, 0.f);
            if (m < NN) v = *(const float4*)(X + (size_t)m * FIN + k0 + c4 * 4);
            *(float4*)&As[r][c4 * 4] = v;
        }
        // B: 20 rows x 64 cols = 320 float4
        for (int idx = tid; idx < KT * 16; idx += 256) {
            int k = idx / 16, c4 = idx % 16;
            *(float4*)&Bs[k][c4 * 4] = *(const float4*)(W0 + (size_t)(k0 + k) * HH + c4 * 4);
        }
        __syncthreads();
#pragma unroll
        for (int k = 0; k < KT; ++k) {
            float a0 = As[ty * 4 + 0][k];
            float a1 = As[ty * 4 + 1][k];
            float a2 = As[ty * 4 + 2][k];
            float a3 = As[ty * 4 + 3][k];
            float4 b = *(float4*)&Bs[k][tx * 4];
            acc[0][0] += a0 * b.x; acc[0][1] += a0 * b.y; acc[0][2] += a0 * b.z; acc[0][3] += a0 * b.w;
            acc[1][0] += a1 * b.x; acc[1][1] += a1 * b.y; acc[1][2] += a1 * b.z; acc[1][3] += a1 * b.w;
            acc[2][0] += a2 * b.x; acc[2][1] += a2 * b.y; acc[2][2] += a2 * b.z; acc[2][3] += a2 * b.w;
            acc[3][0] += a3 * b.x; acc[3][1] += a3 * b.y; acc[3][2] += a3 * b.z; acc[3][3] += a3 * b.w;
        }
        __syncthreads();
    }
    float4 bb = *(const float4*)(b0 + tx * 4);
#pragma unroll
    for (int i = 0; i < 4; ++i) {
        int m = m0 + ty * 4 + i;
        if (m < NN) {
            float4 v;
            v.x = fmaxf(acc[i][0] + bb.x, 0.f);
            v.y = fmaxf(acc[i][1] + bb.y, 0.f);
            v.z = fmaxf(acc[i][2] + bb.z, 0.f);
            v.w = fmaxf(acc[i][3] + bb.w, 0.f);
            *(float4*)(x0 + (size_t)m * HH + tx * 4) = v;
        }
    }
}

// ---------------- fused layer: agg -> mix -> (s @ W) -> relu ----------------
// wave per 4 nodes, lane = feature. N % 4 == 0 so no tail.

__global__ __launch_bounds__(256) void layer_k(const float* __restrict__ hin, const float* __restrict__ x0,
                                               const int2* __restrict__ edata, const int* __restrict__ row_ptr,
                                               const float* __restrict__ W, float beta,
                                               float* __restrict__ hout) {
    __shared__ float Wl[64 * 64];
    __shared__ float Sb[4][4][64];
    int tid = threadIdx.x;
    for (int idx = tid; idx < 1024; idx += 256)
        *(float4*)&Wl[idx * 4] = *(const float4*)(W + idx * 4);
    __syncthreads();

    int lane = tid & 63, w = tid >> 6;
    int gw = blockIdx.x * 4 + w;
    int nw = gridDim.x * 4;
    const int ngroups = NN / 4;  // 25000 exactly

    for (int g = gw; g < ngroups; g += nw) {
        int nbase = g * 4;
        float s[4];
#pragma unroll
        for (int j = 0; j < 4; ++j) {
            int n = nbase + j;
            int p = row_ptr[n], pe = row_ptr[n + 1];
            float acc = 0.f;
            for (; p + 3 < pe; p += 4) {
                int2 e0 = edata[p], e1 = edata[p + 1], e2 = edata[p + 2], e3 = edata[p + 3];
                float v0 = hin[(size_t)e0.x * HH + lane];
                float v1 = hin[(size_t)e1.x * HH + lane];
                float v2 = hin[(size_t)e2.x * HH + lane];
                float v3 = hin[(size_t)e3.x * HH + lane];
                acc += __int_as_float(e0.y) * v0;
                acc += __int_as_float(e1.y) * v1;
                acc += __int_as_float(e2.y) * v2;
                acc += __int_as_float(e3.y) * v3;
            }
            for (; p < pe; ++p) {
                int2 e = edata[p];
                acc += __int_as_float(e.y) * hin[(size_t)e.x * HH + lane];
            }
            acc = (1.f - ALPHA_C) * acc + ALPHA_C * x0[(size_t)n * HH + lane];
            s[j] = acc;
            Sb[w][j][lane] = acc;
        }
        // per-wave LDS region; same-wave write->read ordering handled by compiler waits
        float o0 = 0.f, o1 = 0.f, o2 = 0.f, o3 = 0.f;
#pragma unroll
        for (int f4 = 0; f4 < 64; f4 += 4) {
            float4 s0 = *(const float4*)&Sb[w][0][f4];
            float4 s1 = *(const float4*)&Sb[w][1][f4];
            float4 s2 = *(const float4*)&Sb[w][2][f4];
            float4 s3 = *(const float4*)&Sb[w][3][f4];
            float w0 = Wl[(f4 + 0) * 64 + lane];
            float w1 = Wl[(f4 + 1) * 64 + lane];
            float w2 = Wl[(f4 + 2) * 64 + lane];
            float w3 = Wl[(f4 + 3) * 64 + lane];
            o0 += s0.x * w0 + s0.y * w1 + s0.z * w2 + s0.w * w3;
            o1 += s1.x * w0 + s1.y * w1 + s1.z * w2 + s1.w * w3;
            o2 += s2.x * w0 + s2.y * w1 + s2.z * w2 + s2.w * w3;
            o3 += s3.x * w0 + s3.y * w1 + s3.z * w2 + s3.w * w3;
        }
        float ob = 1.f - beta;
        hout[(size_t)(nbase + 0) * HH + lane] = fmaxf(beta * o0 + ob * s[0], 0.f);
        hout[(size_t)(nbase + 1) * HH + lane] = fmaxf(beta * o1 + ob * s[1], 0.f);
        hout[(size_t)(nbase + 2) * HH + lane] = fmaxf(beta * o2 + ob * s[2], 0.f);
        hout[(size_t)(nbase + 3) * HH + lane] = fmaxf(beta * o3 + ob * s[3], 0.f);
    }
}

// ---------------- output: out = h @ Wout + bout ----------------

__global__ __launch_bounds__(256) void out_k(const float* __restrict__ h, const float* __restrict__ Wout,
                                             const float* __restrict__ bout, float* __restrict__ out) {
    __shared__ float Wl[64 * 40];
    __shared__ float bl[40];
    __shared__ float hrow[4][64];
    int tid = threadIdx.x;
    for (int idx = tid; idx < 64 * 40; idx += 256) Wl[idx] = Wout[idx];
    if (tid < 40) bl[tid] = bout[tid];
    __syncthreads();
    int lane = tid & 63, w = tid >> 6;
    int gw = blockIdx.x * 4 + w;
    int nw = gridDim.x * 4;
    for (int n = gw; n < NN; n += nw) {
        hrow[w][lane] = h[(size_t)n * HH + lane];
        __builtin_amdgcn_s_waitcnt(0);  // lgkmcnt for same-wave LDS write->read
        if (lane < CC) {
            float acc = 0.f;
#pragma unroll
            for (int f = 0; f < 64; ++f) acc += hrow[w][f] * Wl[f * 40 + lane];
            out[(size_t)n * CC + lane] = acc + bl[lane];
        }
    }
}

// ---------------- launch ----------------

extern "C" void kernel_launch(void* const* d_in, const int* in_sizes, int n_in,
                              void* d_out, int out_size, void* d_ws, size_t ws_size,
                              hipStream_t stream) {
    const float* x    = (const float*)d_in[0];
    const int*   ei   = (const int*)d_in[1];
    const int*   rows = ei;
    const int*   cols = ei + EE;
    const float* W0   = (const float*)d_in[2];
    const float* b0   = (const float*)d_in[3];
    const float* Ws   = (const float*)d_in[4];
    const float* Wout = (const float*)d_in[5];
    const float* bout = (const float*)d_in[6];
    float* out = (float*)d_out;

    char* ws = (char*)d_ws;
    size_t o = 0;
    auto alloc = [&](size_t bytes) { void* p = ws + o; o += (bytes + 255) & ~(size_t)255; return p; };
    int*   cnt     = (int*)alloc((size_t)NN * 4);
    float* dinv    = (float*)alloc((size_t)NN * 4);
    int*   row_ptr = (int*)alloc((size_t)(NN + 1) * 4);
    int*   cur     = (int*)alloc((size_t)NN * 4);
    int2*  edata   = (int2*)alloc((size_t)(EE + NN) * 8);
    float* x0      = (float*)alloc((size_t)NN * HH * 4);
    float* hA      = (float*)alloc((size_t)NN * HH * 4);
    float* hB      = (float*)alloc((size_t)NN * HH * 4);

    init_cnt_k<<<(NN + 255) / 256, 256, 0, stream>>>(cnt);
    count_edges_k<<<(EE + 255) / 256, 256, 0, stream>>>(rows, cnt);
    dinv_k<<<(NN + 255) / 256, 256, 0, stream>>>(cnt, dinv);
    scan_k<<<1, 1024, 0, stream>>>(cnt, row_ptr);
    fill_self_k<<<(NN + 255) / 256, 256, 0, stream>>>(row_ptr, dinv, edata, cur);
    fill_edges_k<<<(EE + 255) / 256, 256, 0, stream>>>(rows, cols, dinv, cur, edata);

    proj_k<<<(NN + 63) / 64, 256, 0, stream>>>(x, W0, b0, x0);

    const float* hin = x0;
    float* bufs[2] = {hA, hB};
    for (int l = 0; l < LL; ++l) {
        float beta = logf(0.5f / (float)(l + 1) + 1.0f);
        float* hout = bufs[l & 1];
        layer_k<<<2048, 256, 0, stream>>>(hin, x0, edata, row_ptr,
                                          Ws + (size_t)l * HH * HH, beta, hout);
        hin = hout;
    }

    out_k<<<1024, 256, 0, stream>>>(hin, Wout, bout, out);
}

// Round 6
// 1811.011 us; speedup vs baseline: 1.2553x; 1.2553x over previous
//
#include <hip/hip_runtime.h>
#include <hip/hip_bf16.h>
#include <cmath>

#define NN 100000
#define EE 1250000
#define FIN 500
#define HH 64
#define CC 40
#define LL 16
#define ALPHA_C 0.1f

typedef _Float16 f16x8 __attribute__((ext_vector_type(8)));
typedef _Float16 f16x4 __attribute__((ext_vector_type(4)));
typedef float f32x4 __attribute__((ext_vector_type(4)));

// ---------------- CSR build ----------------

__global__ void init_cnt_k(int* __restrict__ cnt) {
    int i = blockIdx.x * blockDim.x + threadIdx.x;
    if (i < NN) cnt[i] = 1;  // self-loop
}

__global__ void count_edges_k(const int* __restrict__ rows, int* __restrict__ cnt) {
    int e = blockIdx.x * blockDim.x + threadIdx.x;
    if (e < EE) atomicAdd(&cnt[rows[e]], 1);
}

__global__ void dinv_k(const int* __restrict__ cnt, float* __restrict__ dinv) {
    int i = blockIdx.x * blockDim.x + threadIdx.x;
    if (i < NN) dinv[i] = rsqrtf((float)cnt[i]);  // cnt >= 1 always
}

__global__ __launch_bounds__(1024) void scan_k(const int* __restrict__ cnt, int* __restrict__ row_ptr) {
    __shared__ int part[1024];
    const int T = 1024;
    int tid = threadIdx.x;
    const int chunk = (NN + T - 1) / T;  // 98
    int start = tid * chunk;
    int end = min(start + chunk, NN);
    int s = 0;
    for (int i = start; i < end; ++i) s += cnt[i];
    part[tid] = s;
    __syncthreads();
    for (int ofs = 1; ofs < T; ofs <<= 1) {
        int v = (tid >= ofs) ? part[tid - ofs] : 0;
        __syncthreads();
        part[tid] += v;
        __syncthreads();
    }
    int run = (tid > 0) ? part[tid - 1] : 0;
    for (int i = start; i < end; ++i) { row_ptr[i] = run; run += cnt[i]; }
    if (tid == T - 1) row_ptr[NN] = run;
}

__global__ void fill_self_k(const int* __restrict__ row_ptr, const float* __restrict__ dinv,
                            int2* __restrict__ edata, int* __restrict__ cur) {
    int i = blockIdx.x * blockDim.x + threadIdx.x;
    if (i < NN) {
        int p = row_ptr[i];
        float d = dinv[i];
        edata[p] = make_int2(i, __float_as_int(d * d));
        cur[i] = p + 1;
    }
}

__global__ void fill_edges_k(const int* __restrict__ rows, const int* __restrict__ cols,
                             const float* __restrict__ dinv, int* __restrict__ cur,
                             int2* __restrict__ edata) {
    int e = blockIdx.x * blockDim.x + threadIdx.x;
    if (e < EE) {
        int r = rows[e], c = cols[e];
        int p = atomicAdd(&cur[r], 1);
        edata[p] = make_int2(c, __float_as_int(dinv[r] * dinv[c]));
    }
}

// ---------------- input projection: x0 = relu(X @ W0 + b0) ----------------

#define KT 20
__global__ __launch_bounds__(256) void proj_k(const float* __restrict__ X, const float* __restrict__ W0,
                                              const float* __restrict__ b0, float* __restrict__ x0,
                                              _Float16* __restrict__ x0h) {
    __shared__ float As[64][KT];
    __shared__ float Bs[KT][64];
    int tid = threadIdx.x;
    int tx = tid & 15, ty = tid >> 4;
    int m0 = blockIdx.x * 64;
    float acc[4][4] = {};
    for (int k0 = 0; k0 < FIN; k0 += KT) {
        for (int idx = tid; idx < 64 * 5; idx += 256) {
            int r = idx / 5, c4 = idx % 5;
            int m = m0 + r;
            float4 v = make_float4(0.f, 0.f, 0.f, 0.f);
            if (m < NN) v = *(const float4*)(X + (size_t)m * FIN + k0 + c4 * 4);
            *(float4*)&As[r][c4 * 4] = v;
        }
        for (int idx = tid; idx < KT * 16; idx += 256) {
            int k = idx / 16, c4 = idx % 16;
            *(float4*)&Bs[k][c4 * 4] = *(const float4*)(W0 + (size_t)(k0 + k) * HH + c4 * 4);
        }
        __syncthreads();
#pragma unroll
        for (int k4 = 0; k4 < KT; k4 += 4) {
            float4 b0v = *(float4*)&Bs[k4 + 0][tx * 4];
            float4 b1v = *(float4*)&Bs[k4 + 1][tx * 4];
            float4 b2v = *(float4*)&Bs[k4 + 2][tx * 4];
            float4 b3v = *(float4*)&Bs[k4 + 3][tx * 4];
#pragma unroll
            for (int i = 0; i < 4; ++i) {
                float4 a = *(float4*)&As[ty * 4 + i][k4];
                acc[i][0] += a.x * b0v.x + a.y * b1v.x + a.z * b2v.x + a.w * b3v.x;
                acc[i][1] += a.x * b0v.y + a.y * b1v.y + a.z * b2v.y + a.w * b3v.y;
                acc[i][2] += a.x * b0v.z + a.y * b1v.z + a.z * b2v.z + a.w * b3v.z;
                acc[i][3] += a.x * b0v.w + a.y * b1v.w + a.z * b2v.w + a.w * b3v.w;
            }
        }
        __syncthreads();
    }
    float4 bb = *(const float4*)(b0 + tx * 4);
#pragma unroll
    for (int i = 0; i < 4; ++i) {
        int m = m0 + ty * 4 + i;
        if (m < NN) {
            float4 v;
            v.x = fmaxf(acc[i][0] + bb.x, 0.f);
            v.y = fmaxf(acc[i][1] + bb.y, 0.f);
            v.z = fmaxf(acc[i][2] + bb.z, 0.f);
            v.w = fmaxf(acc[i][3] + bb.w, 0.f);
            *(float4*)(x0 + (size_t)m * HH + tx * 4) = v;
            f16x4 hv;
            hv[0] = (_Float16)v.x; hv[1] = (_Float16)v.y;
            hv[2] = (_Float16)v.z; hv[3] = (_Float16)v.w;
            *(f16x4*)(x0h + (size_t)m * HH + tx * 4) = hv;
        }
    }
}

// ---------------- fused layer: agg -> mix -> MFMA transform -> relu ----------------
// block = 16 nodes; wave w gathers nodes w*4..w*4+3 (lane = feature);
// then wave w computes the 16x16 C tile at cols w*16..w*16+15 via 2x mfma_f32_16x16x32_f16.

__global__ __launch_bounds__(256) void layer_k(const _Float16* __restrict__ hin,
                                               const float* __restrict__ x0,
                                               const int2* __restrict__ edata,
                                               const int* __restrict__ row_ptr,
                                               const float* __restrict__ W, float beta,
                                               _Float16* __restrict__ hout) {
    __shared__ float Sb[16][68];           // fp32 s (padded: 4-way -> 0-way on residual read)
    __shared__ _Float16 Sh[16 * 64];       // f16 s, XOR-swizzled rows of 128B
    __shared__ _Float16 Wt[64 * 64];       // Wt[col][k], XOR-swizzled rows of 128B
    char* ShB = (char*)Sh;
    char* WtB = (char*)Wt;
    int tid = threadIdx.x;

    // W[k][c] -> Wt[c][k] (f16, swizzled). Consumed only after the 2nd barrier below.
    for (int idx = tid; idx < HH * HH; idx += 256) {
        int k = idx >> 6, c = idx & 63;
        int b = (c * 128 + k * 2) ^ ((c & 7) << 4);
        *(_Float16*)(WtB + b) = (_Float16)W[idx];
    }

    int lane = tid & 63, w = tid >> 6;
    const int niter = NN / 16;  // 6250
    const float ob = 1.f - beta;

    for (int g = blockIdx.x; g < niter; g += gridDim.x) {
        int nbase = g * 16;
        float s[4];
#pragma unroll
        for (int j = 0; j < 4; ++j) {
            int n = nbase + w * 4 + j;
            int p = row_ptr[n], pe = row_ptr[n + 1];
            float acc0 = 0.f, acc1 = 0.f;
            for (; p + 3 < pe; p += 4) {
                int2 e0 = edata[p], e1 = edata[p + 1], e2 = edata[p + 2], e3 = edata[p + 3];
                float v0 = (float)hin[(size_t)e0.x * HH + lane];
                float v1 = (float)hin[(size_t)e1.x * HH + lane];
                float v2 = (float)hin[(size_t)e2.x * HH + lane];
                float v3 = (float)hin[(size_t)e3.x * HH + lane];
                acc0 += __int_as_float(e0.y) * v0;
                acc1 += __int_as_float(e1.y) * v1;
                acc0 += __int_as_float(e2.y) * v2;
                acc1 += __int_as_float(e3.y) * v3;
            }
            for (; p < pe; ++p) {
                int2 e = edata[p];
                acc0 += __int_as_float(e.y) * (float)hin[(size_t)e.x * HH + lane];
            }
            s[j] = (1.f - ALPHA_C) * (acc0 + acc1) + ALPHA_C * x0[(size_t)n * HH + lane];
        }
        __syncthreads();  // prev iteration's MFMA/residual reads done -> safe to overwrite
#pragma unroll
        for (int j = 0; j < 4; ++j) {
            int nl = w * 4 + j;
            Sb[nl][lane] = s[j];
            int b = (nl * 128 + lane * 2) ^ ((nl & 7) << 4);
            *(_Float16*)(ShB + b) = (_Float16)s[j];
        }
        __syncthreads();  // Sb/Sh (and Wt, first iter) visible to all waves

        // MFMA: C[row=node 0..15][col=w*16+(lane&15)]
        int col = w * 16 + (lane & 15);
        int row = lane & 15;
        int ko = (lane >> 4) * 8;
        f32x4 acc = {0.f, 0.f, 0.f, 0.f};
#pragma unroll
        for (int st = 0; st < 2; ++st) {
            int k0 = ko + st * 32;
            f16x8 af = *(const f16x8*)(ShB + ((row * 128 + k0 * 2) ^ ((row & 7) << 4)));
            f16x8 bf = *(const f16x8*)(WtB + ((col * 128 + k0 * 2) ^ ((col & 7) << 4)));
            acc = __builtin_amdgcn_mfma_f32_16x16x32_f16(af, bf, acc, 0, 0, 0);
        }
#pragma unroll
        for (int r = 0; r < 4; ++r) {
            int nl = (lane >> 4) * 4 + r;
            float sv = Sb[nl][col];
            float v = fmaxf(beta * acc[r] + ob * sv, 0.f);
            hout[(size_t)(nbase + nl) * HH + col] = (_Float16)v;
        }
    }
}

// ---------------- output: out = h @ Wout + bout ----------------

__global__ __launch_bounds__(256) void out_k(const _Float16* __restrict__ h, const float* __restrict__ Wout,
                                             const float* __restrict__ bout, float* __restrict__ out) {
    __shared__ float Wl[64 * 40];
    __shared__ float bl[40];
    __shared__ float hrow[4][64];
    int tid = threadIdx.x;
    for (int idx = tid; idx < 64 * 40; idx += 256) Wl[idx] = Wout[idx];
    if (tid < 40) bl[tid] = bout[tid];
    __syncthreads();
    int lane = tid & 63, w = tid >> 6;
    int gw = blockIdx.x * 4 + w;
    int nw = gridDim.x * 4;
    for (int n = gw; n < NN; n += nw) {
        hrow[w][lane] = (float)h[(size_t)n * HH + lane];
        __builtin_amdgcn_s_waitcnt(0);  // lgkmcnt for same-wave LDS write->read
        if (lane < CC) {
            float acc = 0.f;
#pragma unroll
            for (int f = 0; f < 64; ++f) acc += hrow[w][f] * Wl[f * 40 + lane];
            out[(size_t)n * CC + lane] = acc + bl[lane];
        }
    }
}

// ---------------- launch ----------------

extern "C" void kernel_launch(void* const* d_in, const int* in_sizes, int n_in,
                              void* d_out, int out_size, void* d_ws, size_t ws_size,
                              hipStream_t stream) {
    const float* x    = (const float*)d_in[0];
    const int*   ei   = (const int*)d_in[1];
    const int*   rows = ei;
    const int*   cols = ei + EE;
    const float* W0   = (const float*)d_in[2];
    const float* b0   = (const float*)d_in[3];
    const float* Ws   = (const float*)d_in[4];
    const float* Wout = (const float*)d_in[5];
    const float* bout = (const float*)d_in[6];
    float* out = (float*)d_out;

    char* ws = (char*)d_ws;
    size_t o = 0;
    auto alloc = [&](size_t bytes) { void* p = ws + o; o += (bytes + 255) & ~(size_t)255; return p; };
    int*       cnt     = (int*)alloc((size_t)NN * 4);
    float*     dinv    = (float*)alloc((size_t)NN * 4);
    int*       row_ptr = (int*)alloc((size_t)(NN + 1) * 4);
    int*       cur     = (int*)alloc((size_t)NN * 4);
    int2*      edata   = (int2*)alloc((size_t)(EE + NN) * 8);
    float*     x0      = (float*)alloc((size_t)NN * HH * 4);
    _Float16*  x0h     = (_Float16*)alloc((size_t)NN * HH * 2);
    _Float16*  hA      = (_Float16*)alloc((size_t)NN * HH * 2);
    _Float16*  hB      = (_Float16*)alloc((size_t)NN * HH * 2);

    init_cnt_k<<<(NN + 255) / 256, 256, 0, stream>>>(cnt);
    count_edges_k<<<(EE + 255) / 256, 256, 0, stream>>>(rows, cnt);
    dinv_k<<<(NN + 255) / 256, 256, 0, stream>>>(cnt, dinv);
    scan_k<<<1, 1024, 0, stream>>>(cnt, row_ptr);
    fill_self_k<<<(NN + 255) / 256, 256, 0, stream>>>(row_ptr, dinv, edata, cur);
    fill_edges_k<<<(EE + 255) / 256, 256, 0, stream>>>(rows, cols, dinv, cur, edata);

    proj_k<<<(NN + 63) / 64, 256, 0, stream>>>(x, W0, b0, x0, x0h);

    const _Float16* hin = x0h;
    _Float16* bufs[2] = {hA, hB};
    for (int l = 0; l < LL; ++l) {
        float beta = logf(0.5f / (float)(l + 1) + 1.0f);
        _Float16* hout = bufs[l & 1];
        layer_k<<<2048, 256, 0, stream>>>(hin, x0, edata, row_ptr,
                                          Ws + (size_t)l * HH * HH, beta, hout);
        hin = hout;
    }

    out_k<<<1024, 256, 0, stream>>>(hin, Wout, bout, out);
}

// Round 7
// 1746.906 us; speedup vs baseline: 1.3014x; 1.0367x over previous
//
#include <hip/hip_runtime.h>
#include <hip/hip_bf16.h>
#include <cmath>

#define NN 100000
#define EE 1250000
#define FIN 500
#define HH 64
#define CC 40
#define LL 16
#define ALPHA_C 0.1f

typedef _Float16 f16x8 __attribute__((ext_vector_type(8)));
typedef _Float16 f16x4 __attribute__((ext_vector_type(4)));
typedef float f32x4 __attribute__((ext_vector_type(4)));

// ---------------- CSR build ----------------

__global__ void init_cnt_k(int* __restrict__ cnt) {
    int i = blockIdx.x * blockDim.x + threadIdx.x;
    if (i < NN) cnt[i] = 1;  // self-loop
}

__global__ void count_edges_k(const int* __restrict__ rows, int* __restrict__ cnt) {
    int e = blockIdx.x * blockDim.x + threadIdx.x;
    if (e < EE) atomicAdd(&cnt[rows[e]], 1);
}

__global__ void dinv_k(const int* __restrict__ cnt, float* __restrict__ dinv) {
    int i = blockIdx.x * blockDim.x + threadIdx.x;
    if (i < NN) dinv[i] = rsqrtf((float)cnt[i]);  // cnt >= 1 always
}

__global__ __launch_bounds__(1024) void scan_k(const int* __restrict__ cnt, int* __restrict__ row_ptr) {
    __shared__ int part[1024];
    const int T = 1024;
    int tid = threadIdx.x;
    const int chunk = (NN + T - 1) / T;  // 98
    int start = tid * chunk;
    int end = min(start + chunk, NN);
    int s = 0;
    for (int i = start; i < end; ++i) s += cnt[i];
    part[tid] = s;
    __syncthreads();
    for (int ofs = 1; ofs < T; ofs <<= 1) {
        int v = (tid >= ofs) ? part[tid - ofs] : 0;
        __syncthreads();
        part[tid] += v;
        __syncthreads();
    }
    int run = (tid > 0) ? part[tid - 1] : 0;
    for (int i = start; i < end; ++i) { row_ptr[i] = run; run += cnt[i]; }
    if (tid == T - 1) row_ptr[NN] = run;
}

__global__ void fill_self_k(const int* __restrict__ row_ptr, const float* __restrict__ dinv,
                            int2* __restrict__ edata, int* __restrict__ cur) {
    int i = blockIdx.x * blockDim.x + threadIdx.x;
    if (i < NN) {
        int p = row_ptr[i];
        float d = dinv[i];
        edata[p] = make_int2(i, __float_as_int(d * d));
        cur[i] = p + 1;
    }
}

__global__ void fill_edges_k(const int* __restrict__ rows, const int* __restrict__ cols,
                             const float* __restrict__ dinv, int* __restrict__ cur,
                             int2* __restrict__ edata) {
    int e = blockIdx.x * blockDim.x + threadIdx.x;
    if (e < EE) {
        int r = rows[e], c = cols[e];
        int p = atomicAdd(&cur[r], 1);
        edata[p] = make_int2(c, __float_as_int(dinv[r] * dinv[c]));
    }
}

// ---------------- input projection via MFMA: x0h = f16(relu(X @ W0 + b0)) ----------------
// block = 64 rows x 64 cols; 4 waves, wave w -> rows w*16..w*16+15, all 64 cols.
// K padded 500 -> 512, chunks of 64. X converted fp32->f16 during LDS staging.

__global__ __launch_bounds__(256) void proj_k(const float* __restrict__ X, const float* __restrict__ W0,
                                              const float* __restrict__ b0,
                                              _Float16* __restrict__ x0h) {
    __shared__ _Float16 Asw[64 * 64];  // [row][k] f16, XOR-swizzled 128B rows
    __shared__ _Float16 Bsw[64 * 64];  // [col][k] f16 (W0 transposed), XOR-swizzled
    char* AB = (char*)Asw;
    char* BB = (char*)Bsw;
    int tid = threadIdx.x;
    int lane = tid & 63, w = tid >> 6;
    int m0 = blockIdx.x * 64;
    f32x4 acc[4] = {};

    for (int k0 = 0; k0 < 512; k0 += 64) {
        // stage A: 64 rows x 64 k (fp32 -> f16), float4-granular (500 % 4 == 0)
        for (int t = tid; t < 1024; t += 256) {
            int r = t >> 4, kq = t & 15;
            int k = k0 + kq * 4;
            int m = m0 + r;
            float4 v = make_float4(0.f, 0.f, 0.f, 0.f);
            if (m < NN && k < FIN) v = *(const float4*)(X + (size_t)m * FIN + k);
            f16x4 h;
            h[0] = (_Float16)v.x; h[1] = (_Float16)v.y;
            h[2] = (_Float16)v.z; h[3] = (_Float16)v.w;
            int b = (r * 128 + kq * 8) ^ ((r & 7) << 4);
            *(f16x4*)(AB + b) = h;
        }
        // stage B transposed: W0[k][c] -> Bsw[c][k]
        for (int t = tid; t < 1024; t += 256) {
            int kk = t >> 4, cq = t & 15;
            int k = k0 + kk;
            float4 v = make_float4(0.f, 0.f, 0.f, 0.f);
            if (k < FIN) v = *(const float4*)(W0 + (size_t)k * HH + cq * 4);
#pragma unroll
            for (int j = 0; j < 4; ++j) {
                int c = cq * 4 + j;
                int b = (c * 128 + kk * 2) ^ ((c & 7) << 4);
                *(_Float16*)(BB + b) = (_Float16)((&v.x)[j]);
            }
        }
        __syncthreads();
        int row = lane & 15;
        int ko = (lane >> 4) * 8;
        int ar = w * 16 + row;
#pragma unroll
        for (int st = 0; st < 2; ++st) {
            int k = ko + st * 32;
            f16x8 af = *(const f16x8*)(AB + ((ar * 128 + k * 2) ^ ((ar & 7) << 4)));
#pragma unroll
            for (int nt = 0; nt < 4; ++nt) {
                int c = nt * 16 + row;
                f16x8 bf = *(const f16x8*)(BB + ((c * 128 + k * 2) ^ ((c & 7) << 4)));
                acc[nt] = __builtin_amdgcn_mfma_f32_16x16x32_f16(af, bf, acc[nt], 0, 0, 0);
            }
        }
        __syncthreads();
    }
    // epilogue: C[row=(lane>>4)*4+r][col=lane&15] per 16x16 tile
    int col0 = lane & 15;
    int rg = (lane >> 4) * 4;
#pragma unroll
    for (int nt = 0; nt < 4; ++nt) {
        int c = nt * 16 + col0;
        float bb = b0[c];
#pragma unroll
        for (int r = 0; r < 4; ++r) {
            int m = m0 + w * 16 + rg + r;
            if (m < NN) {
                float v = fmaxf(acc[nt][r] + bb, 0.f);
                x0h[(size_t)m * HH + c] = (_Float16)v;
            }
        }
    }
}

// ---------------- fused layer: agg -> mix -> MFMA transform -> relu ----------------
// block = 16 nodes; wave w gathers nodes w*4..w*4+3 (lane = feature);
// then wave w computes the 16x16 C tile at cols w*16..w*16+15 via 2x mfma_f32_16x16x32_f16.

__global__ __launch_bounds__(256) void layer_k(const _Float16* __restrict__ hin,
                                               const _Float16* __restrict__ x0h,
                                               const int2* __restrict__ edata,
                                               const int* __restrict__ row_ptr,
                                               const float* __restrict__ W, float beta,
                                               _Float16* __restrict__ hout) {
    __shared__ float Sb[16][68];           // fp32 s (padded: 4-way -> 0-way on residual read)
    __shared__ _Float16 Sh[16 * 64];       // f16 s, XOR-swizzled rows of 128B
    __shared__ _Float16 Wt[64 * 64];       // Wt[col][k], XOR-swizzled rows of 128B
    char* ShB = (char*)Sh;
    char* WtB = (char*)Wt;
    int tid = threadIdx.x;

    // W[k][c] -> Wt[c][k] (f16, swizzled). Consumed only after the 2nd barrier below.
    for (int idx = tid; idx < HH * HH; idx += 256) {
        int k = idx >> 6, c = idx & 63;
        int b = (c * 128 + k * 2) ^ ((c & 7) << 4);
        *(_Float16*)(WtB + b) = (_Float16)W[idx];
    }

    int lane = tid & 63, w = tid >> 6;
    const int niter = NN / 16;  // 6250
    const float ob = 1.f - beta;

    for (int g = blockIdx.x; g < niter; g += gridDim.x) {
        int nbase = g * 16;
        float s[4];
#pragma unroll
        for (int j = 0; j < 4; ++j) {
            int n = nbase + w * 4 + j;
            int p = row_ptr[n], pe = row_ptr[n + 1];
            float acc0 = 0.f, acc1 = 0.f;
            for (; p + 3 < pe; p += 4) {
                int2 e0 = edata[p], e1 = edata[p + 1], e2 = edata[p + 2], e3 = edata[p + 3];
                float v0 = (float)hin[(size_t)e0.x * HH + lane];
                float v1 = (float)hin[(size_t)e1.x * HH + lane];
                float v2 = (float)hin[(size_t)e2.x * HH + lane];
                float v3 = (float)hin[(size_t)e3.x * HH + lane];
                acc0 += __int_as_float(e0.y) * v0;
                acc1 += __int_as_float(e1.y) * v1;
                acc0 += __int_as_float(e2.y) * v2;
                acc1 += __int_as_float(e3.y) * v3;
            }
            for (; p < pe; ++p) {
                int2 e = edata[p];
                acc0 += __int_as_float(e.y) * (float)hin[(size_t)e.x * HH + lane];
            }
            s[j] = (1.f - ALPHA_C) * (acc0 + acc1) + ALPHA_C * (float)x0h[(size_t)n * HH + lane];
        }
        __syncthreads();  // prev iteration's MFMA/residual reads done -> safe to overwrite
#pragma unroll
        for (int j = 0; j < 4; ++j) {
            int nl = w * 4 + j;
            Sb[nl][lane] = s[j];
            int b = (nl * 128 + lane * 2) ^ ((nl & 7) << 4);
            *(_Float16*)(ShB + b) = (_Float16)s[j];
        }
        __syncthreads();  // Sb/Sh (and Wt, first iter) visible to all waves

        // MFMA: C[row=node 0..15][col=w*16+(lane&15)]
        int col = w * 16 + (lane & 15);
        int row = lane & 15;
        int ko = (lane >> 4) * 8;
        f32x4 acc = {0.f, 0.f, 0.f, 0.f};
#pragma unroll
        for (int st = 0; st < 2; ++st) {
            int k0 = ko + st * 32;
            f16x8 af = *(const f16x8*)(ShB + ((row * 128 + k0 * 2) ^ ((row & 7) << 4)));
            f16x8 bf = *(const f16x8*)(WtB + ((col * 128 + k0 * 2) ^ ((col & 7) << 4)));
            acc = __builtin_amdgcn_mfma_f32_16x16x32_f16(af, bf, acc, 0, 0, 0);
        }
#pragma unroll
        for (int r = 0; r < 4; ++r) {
            int nl = (lane >> 4) * 4 + r;
            float sv = Sb[nl][col];
            float v = fmaxf(beta * acc[r] + ob * sv, 0.f);
            hout[(size_t)(nbase + nl) * HH + col] = (_Float16)v;
        }
    }
}

// ---------------- output: out = h @ Wout + bout ----------------

__global__ __launch_bounds__(256) void out_k(const _Float16* __restrict__ h, const float* __restrict__ Wout,
                                             const float* __restrict__ bout, float* __restrict__ out) {
    __shared__ float Wl[64 * 40];
    __shared__ float bl[40];
    __shared__ float hrow[4][64];
    int tid = threadIdx.x;
    for (int idx = tid; idx < 64 * 40; idx += 256) Wl[idx] = Wout[idx];
    if (tid < 40) bl[tid] = bout[tid];
    __syncthreads();
    int lane = tid & 63, w = tid >> 6;
    int gw = blockIdx.x * 4 + w;
    int nw = gridDim.x * 4;
    for (int n = gw; n < NN; n += nw) {
        hrow[w][lane] = (float)h[(size_t)n * HH + lane];
        __builtin_amdgcn_s_waitcnt(0);  // lgkmcnt for same-wave LDS write->read
        if (lane < CC) {
            float acc = 0.f;
#pragma unroll
            for (int f = 0; f < 64; ++f) acc += hrow[w][f] * Wl[f * 40 + lane];
            out[(size_t)n * CC + lane] = acc + bl[lane];
        }
    }
}

// ---------------- launch ----------------

extern "C" void kernel_launch(void* const* d_in, const int* in_sizes, int n_in,
                              void* d_out, int out_size, void* d_ws, size_t ws_size,
                              hipStream_t stream) {
    const float* x    = (const float*)d_in[0];
    const int*   ei   = (const int*)d_in[1];
    const int*   rows = ei;
    const int*   cols = ei + EE;
    const float* W0   = (const float*)d_in[2];
    const float* b0   = (const float*)d_in[3];
    const float* Ws   = (const float*)d_in[4];
    const float* Wout = (const float*)d_in[5];
    const float* bout = (const float*)d_in[6];
    float* out = (float*)d_out;

    char* ws = (char*)d_ws;
    size_t o = 0;
    auto alloc = [&](size_t bytes) { void* p = ws + o; o += (bytes + 255) & ~(size_t)255; return p; };
    int*       cnt     = (int*)alloc((size_t)NN * 4);
    float*     dinv    = (float*)alloc((size_t)NN * 4);
    int*       row_ptr = (int*)alloc((size_t)(NN + 1) * 4);
    int*       cur     = (int*)alloc((size_t)NN * 4);
    int2*      edata   = (int2*)alloc((size_t)(EE + NN) * 8);
    _Float16*  x0h     = (_Float16*)alloc((size_t)NN * HH * 2);
    _Float16*  hA      = (_Float16*)alloc((size_t)NN * HH * 2);
    _Float16*  hB      = (_Float16*)alloc((size_t)NN * HH * 2);

    init_cnt_k<<<(NN + 255) / 256, 256, 0, stream>>>(cnt);
    count_edges_k<<<(EE + 255) / 256, 256, 0, stream>>>(rows, cnt);
    dinv_k<<<(NN + 255) / 256, 256, 0, stream>>>(cnt, dinv);
    scan_k<<<1, 1024, 0, stream>>>(cnt, row_ptr);
    fill_self_k<<<(NN + 255) / 256, 256, 0, stream>>>(row_ptr, dinv, edata, cur);
    fill_edges_k<<<(EE + 255) / 256, 256, 0, stream>>>(rows, cols, dinv, cur, edata);

    proj_k<<<(NN + 63) / 64, 256, 0, stream>>>(x, W0, b0, x0h);

    const _Float16* hin = x0h;
    _Float16* bufs[2] = {hA, hB};
    for (int l = 0; l < LL; ++l) {
        float beta = logf(0.5f / (float)(l + 1) + 1.0f);
        _Float16* hout = bufs[l & 1];
        layer_k<<<2048, 256, 0, stream>>>(hin, x0h, edata, row_ptr,
                                          Ws + (size_t)l * HH * HH, beta, hout);
        hin = hout;
    }

    out_k<<<1024, 256, 0, stream>>>(hin, Wout, bout, out);
}

// Round 9
// 1577.227 us; speedup vs baseline: 1.4414x; 1.1076x over previous
//
#include <hip/hip_runtime.h>
#include <hip/hip_bf16.h>
#include <cmath>

#define NN 100000
#define EE 1250000
#define FIN 500
#define HH 64
#define CC 40
#define LL 16
#define ALPHA_C 0.1f
#define SCAN_NB ((NN + 255) / 256)  // 391

typedef _Float16 f16x8 __attribute__((ext_vector_type(8)));
typedef _Float16 f16x4 __attribute__((ext_vector_type(4)));
typedef float f32x4 __attribute__((ext_vector_type(4)));

// ---------------- CSR build ----------------

__global__ void init_cnt_k(int* __restrict__ cnt) {
    int i = blockIdx.x * blockDim.x + threadIdx.x;
    if (i < NN) cnt[i] = 1;  // self-loop
}

__global__ void count_edges_k(const int* __restrict__ rows, int* __restrict__ cnt) {
    int e = blockIdx.x * blockDim.x + threadIdx.x;
    if (e < EE) atomicAdd(&cnt[rows[e]], 1);
}

__global__ void dinv_k(const int* __restrict__ cnt, float* __restrict__ dinv) {
    int i = blockIdx.x * blockDim.x + threadIdx.x;
    if (i < NN) dinv[i] = rsqrtf((float)cnt[i]);  // cnt >= 1 always
}

// 3-kernel parallel exclusive scan of cnt -> row_ptr
__global__ __launch_bounds__(256) void blocksum_k(const int* __restrict__ cnt, int* __restrict__ bsum) {
    __shared__ int red[256];
    int tid = threadIdx.x;
    int i = blockIdx.x * 256 + tid;
    int v = (i < NN) ? cnt[i] : 0;
    red[tid] = v;
    __syncthreads();
    for (int ofs = 128; ofs > 0; ofs >>= 1) {
        if (tid < ofs) red[tid] += red[tid + ofs];
        __syncthreads();
    }
    if (tid == 0) bsum[blockIdx.x] = red[0];
}

__global__ __launch_bounds__(512) void scanbsum_k(int* __restrict__ bsum) {
    __shared__ int part[512];
    int tid = threadIdx.x;
    int v = (tid < SCAN_NB) ? bsum[tid] : 0;
    part[tid] = v;
    __syncthreads();
    for (int ofs = 1; ofs < 512; ofs <<= 1) {
        int t = (tid >= ofs) ? part[tid - ofs] : 0;
        __syncthreads();
        part[tid] += t;
        __syncthreads();
    }
    if (tid < SCAN_NB) bsum[tid] = part[tid] - v;  // exclusive
}

__global__ __launch_bounds__(256) void scatter_rp_k(const int* __restrict__ cnt, const int* __restrict__ bsum,
                                                    int* __restrict__ row_ptr) {
    __shared__ int part[256];
    int tid = threadIdx.x;
    int i = blockIdx.x * 256 + tid;
    int v = (i < NN) ? cnt[i] : 0;
    part[tid] = v;
    __syncthreads();
    for (int ofs = 1; ofs < 256; ofs <<= 1) {
        int t = (tid >= ofs) ? part[tid - ofs] : 0;
        __syncthreads();
        part[tid] += t;
        __syncthreads();
    }
    int incl = part[tid];
    int base = bsum[blockIdx.x];
    if (i < NN) row_ptr[i] = base + incl - v;
    if (i == NN - 1) row_ptr[NN] = base + incl;
}

__global__ void fill_self_k(const int* __restrict__ row_ptr, const float* __restrict__ dinv,
                            int2* __restrict__ edata, int* __restrict__ cur) {
    int i = blockIdx.x * blockDim.x + threadIdx.x;
    if (i < NN) {
        int p = row_ptr[i];
        float d = dinv[i];
        edata[p] = make_int2(i, __float_as_int(d * d));
        cur[i] = p + 1;
    }
}

__global__ void fill_edges_k(const int* __restrict__ rows, const int* __restrict__ cols,
                             const float* __restrict__ dinv, int* __restrict__ cur,
                             int2* __restrict__ edata) {
    int e = blockIdx.x * blockDim.x + threadIdx.x;
    if (e < EE) {
        int r = rows[e], c = cols[e];
        int p = atomicAdd(&cur[r], 1);
        edata[p] = make_int2(c, __float_as_int(dinv[r] * dinv[c]));
    }
}

// ---------------- input projection via MFMA: x0h = f16(relu(X @ W0 + b0)) ----------------

__global__ __launch_bounds__(256) void proj_k(const float* __restrict__ X, const float* __restrict__ W0,
                                              const float* __restrict__ b0,
                                              _Float16* __restrict__ x0h) {
    __shared__ _Float16 Asw[64 * 64];  // [row][k] f16, XOR-swizzled 128B rows
    __shared__ _Float16 Bsw[64 * 64];  // [col][k] f16 (W0 transposed), XOR-swizzled
    char* AB = (char*)Asw;
    char* BB = (char*)Bsw;
    int tid = threadIdx.x;
    int lane = tid & 63, w = tid >> 6;
    int m0 = blockIdx.x * 64;
    f32x4 acc[4] = {};

    for (int k0 = 0; k0 < 512; k0 += 64) {
        for (int t = tid; t < 1024; t += 256) {
            int r = t >> 4, kq = t & 15;
            int k = k0 + kq * 4;
            int m = m0 + r;
            float4 v = make_float4(0.f, 0.f, 0.f, 0.f);
            if (m < NN && k < FIN) v = *(const float4*)(X + (size_t)m * FIN + k);
            f16x4 h;
            h[0] = (_Float16)v.x; h[1] = (_Float16)v.y;
            h[2] = (_Float16)v.z; h[3] = (_Float16)v.w;
            int b = (r * 128 + kq * 8) ^ ((r & 7) << 4);
            *(f16x4*)(AB + b) = h;
        }
        for (int t = tid; t < 1024; t += 256) {
            int kk = t >> 4, cq = t & 15;
            int k = k0 + kk;
            float4 v = make_float4(0.f, 0.f, 0.f, 0.f);
            if (k < FIN) v = *(const float4*)(W0 + (size_t)k * HH + cq * 4);
#pragma unroll
            for (int j = 0; j < 4; ++j) {
                int c = cq * 4 + j;
                int b = (c * 128 + kk * 2) ^ ((c & 7) << 4);
                *(_Float16*)(BB + b) = (_Float16)((&v.x)[j]);
            }
        }
        __syncthreads();
        int row = lane & 15;
        int ko = (lane >> 4) * 8;
        int ar = w * 16 + row;
#pragma unroll
        for (int st = 0; st < 2; ++st) {
            int k = ko + st * 32;
            f16x8 af = *(const f16x8*)(AB + ((ar * 128 + k * 2) ^ ((ar & 7) << 4)));
#pragma unroll
            for (int nt = 0; nt < 4; ++nt) {
                int c = nt * 16 + row;
                f16x8 bf = *(const f16x8*)(BB + ((c * 128 + k * 2) ^ ((c & 7) << 4)));
                acc[nt] = __builtin_amdgcn_mfma_f32_16x16x32_f16(af, bf, acc[nt], 0, 0, 0);
            }
        }
        __syncthreads();
    }
    int col0 = lane & 15;
    int rg = (lane >> 4) * 4;
#pragma unroll
    for (int nt = 0; nt < 4; ++nt) {
        int c = nt * 16 + col0;
        float bb = b0[c];
#pragma unroll
        for (int r = 0; r < 4; ++r) {
            int m = m0 + w * 16 + rg + r;
            if (m < NN) {
                float v = fmaxf(acc[nt][r] + bb, 0.f);
                x0h[(size_t)m * HH + c] = (_Float16)v;
            }
        }
    }
}

// ---------------- fused layer: agg -> mix -> MFMA transform -> relu ----------------

__global__ __launch_bounds__(256) void layer_k(const _Float16* __restrict__ hin,
                                               const _Float16* __restrict__ x0h,
                                               const int2* __restrict__ edata,
                                               const int* __restrict__ row_ptr,
                                               const float* __restrict__ W, float beta,
                                               _Float16* __restrict__ hout) {
    __shared__ float Sb[16][68];           // fp32 s (padded: 4-way -> 0-way on residual read)
    __shared__ _Float16 Sh[16 * 64];       // f16 s, XOR-swizzled rows of 128B
    __shared__ _Float16 Wt[64 * 64];       // Wt[col][k], XOR-swizzled rows of 128B
    char* ShB = (char*)Sh;
    char* WtB = (char*)Wt;
    int tid = threadIdx.x;

    for (int idx = tid; idx < HH * HH; idx += 256) {
        int k = idx >> 6, c = idx & 63;
        int b = (c * 128 + k * 2) ^ ((c & 7) << 4);
        *(_Float16*)(WtB + b) = (_Float16)W[idx];
    }

    int lane = tid & 63, w = tid >> 6;
    const int niter = NN / 16;  // 6250
    const float ob = 1.f - beta;

    for (int g = blockIdx.x; g < niter; g += gridDim.x) {
        int nbase = g * 16;
        float s[4];
#pragma unroll
        for (int j = 0; j < 4; ++j) {
            int n = nbase + w * 4 + j;
            int p = row_ptr[n], pe = row_ptr[n + 1];
            float acc0 = 0.f, acc1 = 0.f;
            for (; p + 3 < pe; p += 4) {
                int2 e0 = edata[p], e1 = edata[p + 1], e2 = edata[p + 2], e3 = edata[p + 3];
                float v0 = (float)hin[(size_t)e0.x * HH + lane];
                float v1 = (float)hin[(size_t)e1.x * HH + lane];
                float v2 = (float)hin[(size_t)e2.x * HH + lane];
                float v3 = (float)hin[(size_t)e3.x * HH + lane];
                acc0 += __int_as_float(e0.y) * v0;
                acc1 += __int_as_float(e1.y) * v1;
                acc0 += __int_as_float(e2.y) * v2;
                acc1 += __int_as_float(e3.y) * v3;
            }
            for (; p < pe; ++p) {
                int2 e = edata[p];
                acc0 += __int_as_float(e.y) * (float)hin[(size_t)e.x * HH + lane];
            }
            s[j] = (1.f - ALPHA_C) * (acc0 + acc1) + ALPHA_C * (float)x0h[(size_t)n * HH + lane];
        }
        __syncthreads();  // prev iteration's MFMA/residual reads done -> safe to overwrite
#pragma unroll
        for (int j = 0; j < 4; ++j) {
            int nl = w * 4 + j;
            Sb[nl][lane] = s[j];
            int b = (nl * 128 + lane * 2) ^ ((nl & 7) << 4);
            *(_Float16*)(ShB + b) = (_Float16)s[j];
        }
        __syncthreads();  // Sb/Sh (and Wt, first iter) visible to all waves

        int col = w * 16 + (lane & 15);
        int row = lane & 15;
        int ko = (lane >> 4) * 8;
        f32x4 acc = {0.f, 0.f, 0.f, 0.f};
#pragma unroll
        for (int st = 0; st < 2; ++st) {
            int k0 = ko + st * 32;
            f16x8 af = *(const f16x8*)(ShB + ((row * 128 + k0 * 2) ^ ((row & 7) << 4)));
            f16x8 bf = *(const f16x8*)(WtB + ((col * 128 + k0 * 2) ^ ((col & 7) << 4)));
            acc = __builtin_amdgcn_mfma_f32_16x16x32_f16(af, bf, acc, 0, 0, 0);
        }
#pragma unroll
        for (int r = 0; r < 4; ++r) {
            int nl = (lane >> 4) * 4 + r;
            float sv = Sb[nl][col];
            float v = fmaxf(beta * acc[r] + ob * sv, 0.f);
            hout[(size_t)(nbase + nl) * HH + col] = (_Float16)v;
        }
    }
}

// ---------------- output: out = h @ Wout + bout ----------------

__global__ __launch_bounds__(256) void out_k(const _Float16* __restrict__ h, const float* __restrict__ Wout,
                                             const float* __restrict__ bout, float* __restrict__ out) {
    __shared__ float Wl[64 * 40];
    __shared__ float bl[40];
    __shared__ float hrow[4][64];
    int tid = threadIdx.x;
    for (int idx = tid; idx < 64 * 40; idx += 256) Wl[idx] = Wout[idx];
    if (tid < 40) bl[tid] = bout[tid];
    __syncthreads();
    int lane = tid & 63, w = tid >> 6;
    int gw = blockIdx.x * 4 + w;
    int nw = gridDim.x * 4;
    for (int n = gw; n < NN; n += nw) {
        hrow[w][lane] = (float)h[(size_t)n * HH + lane];
        __builtin_amdgcn_s_waitcnt(0);  // lgkmcnt for same-wave LDS write->read
        if (lane < CC) {
            float acc = 0.f;
#pragma unroll
            for (int f = 0; f < 64; ++f) acc += hrow[w][f] * Wl[f * 40 + lane];
            out[(size_t)n * CC + lane] = acc + bl[lane];
        }
    }
}

// ---------------- launch ----------------

extern "C" void kernel_launch(void* const* d_in, const int* in_sizes, int n_in,
                              void* d_out, int out_size, void* d_ws, size_t ws_size,
                              hipStream_t stream) {
    const float* x    = (const float*)d_in[0];
    const int*   ei   = (const int*)d_in[1];
    const int*   rows = ei;
    const int*   cols = ei + EE;
    const float* W0   = (const float*)d_in[2];
    const float* b0   = (const float*)d_in[3];
    const float* Ws   = (const float*)d_in[4];
    const float* Wout = (const float*)d_in[5];
    const float* bout = (const float*)d_in[6];
    float* out = (float*)d_out;

    char* ws = (char*)d_ws;
    size_t o = 0;
    auto alloc = [&](size_t bytes) { void* p = ws + o; o += (bytes + 255) & ~(size_t)255; return p; };
    int*       cnt     = (int*)alloc((size_t)NN * 4);
    float*     dinv    = (float*)alloc((size_t)NN * 4);
    int*       row_ptr = (int*)alloc((size_t)(NN + 1) * 4);
    int*       cur     = (int*)alloc((size_t)NN * 4);
    int*       bsum    = (int*)alloc((size_t)SCAN_NB * 4);
    int2*      edata   = (int2*)alloc((size_t)(EE + NN) * 8);
    _Float16*  x0h     = (_Float16*)alloc((size_t)NN * HH * 2);
    _Float16*  hA      = (_Float16*)alloc((size_t)NN * HH * 2);
    _Float16*  hB      = (_Float16*)alloc((size_t)NN * HH * 2);

    init_cnt_k<<<(NN + 255) / 256, 256, 0, stream>>>(cnt);
    count_edges_k<<<(EE + 255) / 256, 256, 0, stream>>>(rows, cnt);
    dinv_k<<<(NN + 255) / 256, 256, 0, stream>>>(cnt, dinv);
    blocksum_k<<<SCAN_NB, 256, 0, stream>>>(cnt, bsum);
    scanbsum_k<<<1, 512, 0, stream>>>(bsum);
    scatter_rp_k<<<SCAN_NB, 256, 0, stream>>>(cnt, bsum, row_ptr);
    fill_self_k<<<(NN + 255) / 256, 256, 0, stream>>>(row_ptr, dinv, edata, cur);
    fill_edges_k<<<(EE + 255) / 256, 256, 0, stream>>>(rows, cols, dinv, cur, edata);

    proj_k<<<(NN + 63) / 64, 256, 0, stream>>>(x, W0, b0, x0h);

    const _Float16* hin = x0h;
    _Float16* bufs[2] = {hA, hB};
    for (int l = 0; l < LL; ++l) {
        float beta = logf(0.5f / (float)(l + 1) + 1.0f);
        _Float16* hout = bufs[l & 1];
        layer_k<<<2048, 256, 0, stream>>>(hin, x0h, edata, row_ptr,
                                          Ws + (size_t)l * HH * HH, beta, hout);
        hin = hout;
    }

    out_k<<<1024, 256, 0, stream>>>(hin, Wout, bout, out);
}

// Round 10
// 1247.995 us; speedup vs baseline: 1.8216x; 1.2638x over previous
//
#include <hip/hip_runtime.h>
#include <hip/hip_bf16.h>
#include <cmath>

#define NN 100000
#define EE 1250000
#define FIN 500
#define HH 64
#define CC 40
#define LL 16
#define ALPHA_C 0.1f
#define SCAN_NB ((NN + 255) / 256)  // 391

typedef _Float16 f16x8 __attribute__((ext_vector_type(8)));
typedef _Float16 f16x4 __attribute__((ext_vector_type(4)));
typedef float f32x4 __attribute__((ext_vector_type(4)));

// ---------------- CSR build ----------------

__global__ void init_cnt_k(int* __restrict__ cnt) {
    int i = blockIdx.x * blockDim.x + threadIdx.x;
    if (i < NN) cnt[i] = 1;  // self-loop
}

__global__ void count_edges_k(const int* __restrict__ rows, int* __restrict__ cnt) {
    int e = blockIdx.x * blockDim.x + threadIdx.x;
    if (e < EE) atomicAdd(&cnt[rows[e]], 1);
}

__global__ void dinv_k(const int* __restrict__ cnt, float* __restrict__ dinv) {
    int i = blockIdx.x * blockDim.x + threadIdx.x;
    if (i < NN) dinv[i] = rsqrtf((float)cnt[i]);  // cnt >= 1 always
}

// 3-kernel parallel exclusive scan of cnt -> row_ptr
__global__ __launch_bounds__(256) void blocksum_k(const int* __restrict__ cnt, int* __restrict__ bsum) {
    __shared__ int red[256];
    int tid = threadIdx.x;
    int i = blockIdx.x * 256 + tid;
    int v = (i < NN) ? cnt[i] : 0;
    red[tid] = v;
    __syncthreads();
    for (int ofs = 128; ofs > 0; ofs >>= 1) {
        if (tid < ofs) red[tid] += red[tid + ofs];
        __syncthreads();
    }
    if (tid == 0) bsum[blockIdx.x] = red[0];
}

__global__ __launch_bounds__(512) void scanbsum_k(int* __restrict__ bsum) {
    __shared__ int part[512];
    int tid = threadIdx.x;
    int v = (tid < SCAN_NB) ? bsum[tid] : 0;
    part[tid] = v;
    __syncthreads();
    for (int ofs = 1; ofs < 512; ofs <<= 1) {
        int t = (tid >= ofs) ? part[tid - ofs] : 0;
        __syncthreads();
        part[tid] += t;
        __syncthreads();
    }
    if (tid < SCAN_NB) bsum[tid] = part[tid] - v;  // exclusive
}

__global__ __launch_bounds__(256) void scatter_rp_k(const int* __restrict__ cnt, const int* __restrict__ bsum,
                                                    int* __restrict__ row_ptr) {
    __shared__ int part[256];
    int tid = threadIdx.x;
    int i = blockIdx.x * 256 + tid;
    int v = (i < NN) ? cnt[i] : 0;
    part[tid] = v;
    __syncthreads();
    for (int ofs = 1; ofs < 256; ofs <<= 1) {
        int t = (tid >= ofs) ? part[tid - ofs] : 0;
        __syncthreads();
        part[tid] += t;
        __syncthreads();
    }
    int incl = part[tid];
    int base = bsum[blockIdx.x];
    if (i < NN) row_ptr[i] = base + incl - v;
    if (i == NN - 1) row_ptr[NN] = base + incl;
}

__global__ void fill_self_k(const int* __restrict__ row_ptr, const float* __restrict__ dinv,
                            int2* __restrict__ edata, int* __restrict__ cur) {
    int i = blockIdx.x * blockDim.x + threadIdx.x;
    if (i < NN) {
        int p = row_ptr[i];
        float d = dinv[i];
        edata[p] = make_int2(i, __float_as_int(d * d));
        cur[i] = p + 1;
    }
}

__global__ void fill_edges_k(const int* __restrict__ rows, const int* __restrict__ cols,
                             const float* __restrict__ dinv, int* __restrict__ cur,
                             int2* __restrict__ edata) {
    int e = blockIdx.x * blockDim.x + threadIdx.x;
    if (e < EE) {
        int r = rows[e], c = cols[e];
        int p = atomicAdd(&cur[r], 1);
        edata[p] = make_int2(c, __float_as_int(dinv[r] * dinv[c]));
    }
}

// ---------------- input projection via MFMA: x0h = f16(relu(X @ W0 + b0)) ----------------

__global__ __launch_bounds__(256) void proj_k(const float* __restrict__ X, const float* __restrict__ W0,
                                              const float* __restrict__ b0,
                                              _Float16* __restrict__ x0h) {
    __shared__ _Float16 Asw[64 * 64];  // [row][k] f16, XOR-swizzled 128B rows
    __shared__ _Float16 Bsw[64 * 64];  // [col][k] f16 (W0 transposed), XOR-swizzled
    char* AB = (char*)Asw;
    char* BB = (char*)Bsw;
    int tid = threadIdx.x;
    int lane = tid & 63, w = tid >> 6;
    int m0 = blockIdx.x * 64;
    f32x4 acc[4] = {};

    for (int k0 = 0; k0 < 512; k0 += 64) {
        for (int t = tid; t < 1024; t += 256) {
            int r = t >> 4, kq = t & 15;
            int k = k0 + kq * 4;
            int m = m0 + r;
            float4 v = make_float4(0.f, 0.f, 0.f, 0.f);
            if (m < NN && k < FIN) v = *(const float4*)(X + (size_t)m * FIN + k);
            f16x4 h;
            h[0] = (_Float16)v.x; h[1] = (_Float16)v.y;
            h[2] = (_Float16)v.z; h[3] = (_Float16)v.w;
            int b = (r * 128 + kq * 8) ^ ((r & 7) << 4);
            *(f16x4*)(AB + b) = h;
        }
        for (int t = tid; t < 1024; t += 256) {
            int kk = t >> 4, cq = t & 15;
            int k = k0 + kk;
            float4 v = make_float4(0.f, 0.f, 0.f, 0.f);
            if (k < FIN) v = *(const float4*)(W0 + (size_t)k * HH + cq * 4);
#pragma unroll
            for (int j = 0; j < 4; ++j) {
                int c = cq * 4 + j;
                int b = (c * 128 + kk * 2) ^ ((c & 7) << 4);
                *(_Float16*)(BB + b) = (_Float16)((&v.x)[j]);
            }
        }
        __syncthreads();
        int row = lane & 15;
        int ko = (lane >> 4) * 8;
        int ar = w * 16 + row;
#pragma unroll
        for (int st = 0; st < 2; ++st) {
            int k = ko + st * 32;
            f16x8 af = *(const f16x8*)(AB + ((ar * 128 + k * 2) ^ ((ar & 7) << 4)));
#pragma unroll
            for (int nt = 0; nt < 4; ++nt) {
                int c = nt * 16 + row;
                f16x8 bf = *(const f16x8*)(BB + ((c * 128 + k * 2) ^ ((c & 7) << 4)));
                acc[nt] = __builtin_amdgcn_mfma_f32_16x16x32_f16(af, bf, acc[nt], 0, 0, 0);
            }
        }
        __syncthreads();
    }
    int col0 = lane & 15;
    int rg = (lane >> 4) * 4;
#pragma unroll
    for (int nt = 0; nt < 4; ++nt) {
        int c = nt * 16 + col0;
        float bb = b0[c];
#pragma unroll
        for (int r = 0; r < 4; ++r) {
            int m = m0 + w * 16 + rg + r;
            if (m < NN) {
                float v = fmaxf(acc[nt][r] + bb, 0.f);
                x0h[(size_t)m * HH + c] = (_Float16)v;
            }
        }
    }
}

// ---------------- fused layer: agg -> mix -> MFMA transform -> relu ----------------
// Gather: batch-8 edge unroll (8 rows in flight), scalar (s_load) edge descriptors,
// nontemporal on residual/output streams to keep L2 for hin gather lines.

__global__ __launch_bounds__(256) void layer_k(const _Float16* __restrict__ hin,
                                               const _Float16* __restrict__ x0h,
                                               const int2* __restrict__ edata,
                                               const int* __restrict__ row_ptr,
                                               const float* __restrict__ W, float beta,
                                               _Float16* __restrict__ hout) {
    __shared__ float Sb[16][68];           // fp32 s (padded)
    __shared__ _Float16 Sh[16 * 64];       // f16 s, XOR-swizzled rows of 128B
    __shared__ _Float16 Wt[64 * 64];       // Wt[col][k], XOR-swizzled rows of 128B
    char* ShB = (char*)Sh;
    char* WtB = (char*)Wt;
    int tid = threadIdx.x;

    for (int idx = tid; idx < HH * HH; idx += 256) {
        int k = idx >> 6, c = idx & 63;
        int b = (c * 128 + k * 2) ^ ((c & 7) << 4);
        *(_Float16*)(WtB + b) = (_Float16)W[idx];
    }

    int lane = tid & 63, w = tid >> 6;
    const int niter = NN / 16;  // 6250
    const float ob = 1.f - beta;

    for (int g = blockIdx.x; g < niter; g += gridDim.x) {
        int nbase = g * 16;
        float s[4];
#pragma unroll
        for (int j = 0; j < 4; ++j) {
            int n = nbase + w * 4 + j;
            int p  = __builtin_amdgcn_readfirstlane(row_ptr[n]);
            int pe = __builtin_amdgcn_readfirstlane(row_ptr[n + 1]);
            float acc0 = 0.f, acc1 = 0.f;
            // batch-8: descriptors via scalar loads, 8 row loads in flight
            for (; p + 7 < pe; p += 8) {
                int2 e0 = edata[p + 0], e1 = edata[p + 1], e2 = edata[p + 2], e3 = edata[p + 3];
                int2 e4 = edata[p + 4], e5 = edata[p + 5], e6 = edata[p + 6], e7 = edata[p + 7];
                float v0 = (float)hin[(size_t)e0.x * HH + lane];
                float v1 = (float)hin[(size_t)e1.x * HH + lane];
                float v2 = (float)hin[(size_t)e2.x * HH + lane];
                float v3 = (float)hin[(size_t)e3.x * HH + lane];
                float v4 = (float)hin[(size_t)e4.x * HH + lane];
                float v5 = (float)hin[(size_t)e5.x * HH + lane];
                float v6 = (float)hin[(size_t)e6.x * HH + lane];
                float v7 = (float)hin[(size_t)e7.x * HH + lane];
                acc0 += __int_as_float(e0.y) * v0;
                acc1 += __int_as_float(e1.y) * v1;
                acc0 += __int_as_float(e2.y) * v2;
                acc1 += __int_as_float(e3.y) * v3;
                acc0 += __int_as_float(e4.y) * v4;
                acc1 += __int_as_float(e5.y) * v5;
                acc0 += __int_as_float(e6.y) * v6;
                acc1 += __int_as_float(e7.y) * v7;
            }
            for (; p + 3 < pe; p += 4) {
                int2 e0 = edata[p], e1 = edata[p + 1], e2 = edata[p + 2], e3 = edata[p + 3];
                float v0 = (float)hin[(size_t)e0.x * HH + lane];
                float v1 = (float)hin[(size_t)e1.x * HH + lane];
                float v2 = (float)hin[(size_t)e2.x * HH + lane];
                float v3 = (float)hin[(size_t)e3.x * HH + lane];
                acc0 += __int_as_float(e0.y) * v0;
                acc1 += __int_as_float(e1.y) * v1;
                acc0 += __int_as_float(e2.y) * v2;
                acc1 += __int_as_float(e3.y) * v3;
            }
            for (; p < pe; ++p) {
                int2 e = edata[p];
                acc0 += __int_as_float(e.y) * (float)hin[(size_t)e.x * HH + lane];
            }
            float xv = (float)__builtin_nontemporal_load(&x0h[(size_t)n * HH + lane]);
            s[j] = (1.f - ALPHA_C) * (acc0 + acc1) + ALPHA_C * xv;
        }
        __syncthreads();  // prev iteration's MFMA/residual reads done -> safe to overwrite
#pragma unroll
        for (int j = 0; j < 4; ++j) {
            int nl = w * 4 + j;
            Sb[nl][lane] = s[j];
            int b = (nl * 128 + lane * 2) ^ ((nl & 7) << 4);
            *(_Float16*)(ShB + b) = (_Float16)s[j];
        }
        __syncthreads();  // Sb/Sh (and Wt, first iter) visible to all waves

        int col = w * 16 + (lane & 15);
        int row = lane & 15;
        int ko = (lane >> 4) * 8;
        f32x4 acc = {0.f, 0.f, 0.f, 0.f};
#pragma unroll
        for (int st = 0; st < 2; ++st) {
            int k0 = ko + st * 32;
            f16x8 af = *(const f16x8*)(ShB + ((row * 128 + k0 * 2) ^ ((row & 7) << 4)));
            f16x8 bf = *(const f16x8*)(WtB + ((col * 128 + k0 * 2) ^ ((col & 7) << 4)));
            acc = __builtin_amdgcn_mfma_f32_16x16x32_f16(af, bf, acc, 0, 0, 0);
        }
#pragma unroll
        for (int r = 0; r < 4; ++r) {
            int nl = (lane >> 4) * 4 + r;
            float sv = Sb[nl][col];
            float v = fmaxf(beta * acc[r] + ob * sv, 0.f);
            __builtin_nontemporal_store((_Float16)v, &hout[(size_t)(nbase + nl) * HH + col]);
        }
    }
}

// ---------------- output: out = h @ Wout + bout ----------------

__global__ __launch_bounds__(256) void out_k(const _Float16* __restrict__ h, const float* __restrict__ Wout,
                                             const float* __restrict__ bout, float* __restrict__ out) {
    __shared__ float Wl[64 * 40];
    __shared__ float bl[40];
    __shared__ float hrow[4][64];
    int tid = threadIdx.x;
    for (int idx = tid; idx < 64 * 40; idx += 256) Wl[idx] = Wout[idx];
    if (tid < 40) bl[tid] = bout[tid];
    __syncthreads();
    int lane = tid & 63, w = tid >> 6;
    int gw = blockIdx.x * 4 + w;
    int nw = gridDim.x * 4;
    for (int n = gw; n < NN; n += nw) {
        hrow[w][lane] = (float)h[(size_t)n * HH + lane];
        __builtin_amdgcn_s_waitcnt(0);  // lgkmcnt for same-wave LDS write->read
        if (lane < CC) {
            float acc = 0.f;
#pragma unroll
            for (int f = 0; f < 64; ++f) acc += hrow[w][f] * Wl[f * 40 + lane];
            out[(size_t)n * CC + lane] = acc + bl[lane];
        }
    }
}

// ---------------- launch ----------------

extern "C" void kernel_launch(void* const* d_in, const int* in_sizes, int n_in,
                              void* d_out, int out_size, void* d_ws, size_t ws_size,
                              hipStream_t stream) {
    const float* x    = (const float*)d_in[0];
    const int*   ei   = (const int*)d_in[1];
    const int*   rows = ei;
    const int*   cols = ei + EE;
    const float* W0   = (const float*)d_in[2];
    const float* b0   = (const float*)d_in[3];
    const float* Ws   = (const float*)d_in[4];
    const float* Wout = (const float*)d_in[5];
    const float* bout = (const float*)d_in[6];
    float* out = (float*)d_out;

    char* ws = (char*)d_ws;
    size_t o = 0;
    auto alloc = [&](size_t bytes) { void* p = ws + o; o += (bytes + 255) & ~(size_t)255; return p; };
    int*       cnt     = (int*)alloc((size_t)NN * 4);
    float*     dinv    = (float*)alloc((size_t)NN * 4);
    int*       row_ptr = (int*)alloc((size_t)(NN + 1) * 4);
    int*       cur     = (int*)alloc((size_t)NN * 4);
    int*       bsum    = (int*)alloc((size_t)SCAN_NB * 4);
    int2*      edata   = (int2*)alloc((size_t)(EE + NN) * 8);
    _Float16*  x0h     = (_Float16*)alloc((size_t)NN * HH * 2);
    _Float16*  hA      = (_Float16*)alloc((size_t)NN * HH * 2);
    _Float16*  hB      = (_Float16*)alloc((size_t)NN * HH * 2);

    init_cnt_k<<<(NN + 255) / 256, 256, 0, stream>>>(cnt);
    count_edges_k<<<(EE + 255) / 256, 256, 0, stream>>>(rows, cnt);
    dinv_k<<<(NN + 255) / 256, 256, 0, stream>>>(cnt, dinv);
    blocksum_k<<<SCAN_NB, 256, 0, stream>>>(cnt, bsum);
    scanbsum_k<<<1, 512, 0, stream>>>(bsum);
    scatter_rp_k<<<SCAN_NB, 256, 0, stream>>>(cnt, bsum, row_ptr);
    fill_self_k<<<(NN + 255) / 256, 256, 0, stream>>>(row_ptr, dinv, edata, cur);
    fill_edges_k<<<(EE + 255) / 256, 256, 0, stream>>>(rows, cols, dinv, cur, edata);

    proj_k<<<(NN + 63) / 64, 256, 0, stream>>>(x, W0, b0, x0h);

    const _Float16* hin = x0h;
    _Float16* bufs[2] = {hA, hB};
    for (int l = 0; l < LL; ++l) {
        float beta = logf(0.5f / (float)(l + 1) + 1.0f);
        _Float16* hout = bufs[l & 1];
        layer_k<<<2048, 256, 0, stream>>>(hin, x0h, edata, row_ptr,
                                          Ws + (size_t)l * HH * HH, beta, hout);
        hin = hout;
    }

    out_k<<<1024, 256, 0, stream>>>(hin, Wout, bout, out);
}